// Round 6
// baseline (247.063 us; speedup 1.0000x reference)
//
#include <hip/hip_runtime.h>
#include <math.h>

#define S_LEN 8192
#define DHEAD 64
#define NBATCH 4
#define BK 32

typedef unsigned short u16;
typedef unsigned int u32;
typedef __attribute__((ext_vector_type(8))) _Float16 half8;
typedef __attribute__((ext_vector_type(2))) __fp16 fp16x2;
typedef __attribute__((ext_vector_type(4))) float f32x4;

union HU8 { int4 i4; half8 h8; u32 w[4]; };
union H2U { fp16x2 h2; u32 w; };
union HU  { _Float16 h; u16 u; };

#if __has_builtin(__builtin_amdgcn_exp2f)
#define EXP2(x) __builtin_amdgcn_exp2f(x)
#else
#define EXP2(x) exp2f(x)
#endif

// float -> f16 RNE
__device__ __forceinline__ u16 f2h(float f) {
    HU x; x.h = (_Float16)f; return x.u;
}
// two floats -> packed f16x2, single v_cvt_pkrtz_f16_f32
__device__ __forceinline__ u32 packh2(float a, float b) {
    H2U x; x.h2 = __builtin_amdgcn_cvt_pkrtz(a, b); return x.w;
}

// ---------------------------------------------------------------------------
// Prep: blocks [0,1024) pack K and V (both f16) of one 32-key tile
// (b = bid>>8, t = bid&255) into MFMA-fragment order:
//   blob[b][t] (8 KB) = K chunks j=0..3 (j=kt*2+ds) then V chunks dt=0..3,
//   chunk = 64 lanes x 16 B, exact flash lane order:
//     K: lane(low,h) -> K[b][t*32 + 8*(low>>2)+4*kt+(low&3)][ds*32+h*8+0..7]
//     V: lane(low,h) -> V[b][t*32 + h*8 + 0..7][dt*16+low]
// Blocks [1024,1056): Julia bias in f64 (matches numpy), fixed max M=20
// folded: bias2[k] = log(exp(et*scale)+1e-8)*log2e - 20.
// ---------------------------------------------------------------------------
__global__ void prep_kernel(const float* __restrict__ K, const float* __restrict__ V,
                            const float* crp, const float* cip, const float* scp,
                            u16* __restrict__ blob, float* __restrict__ bias2) {
    int bid = blockIdx.x, tid = threadIdx.x;
    if (bid < 1024) {
        int b = bid >> 8, t = bid & 255;
        __shared__ float Kt[32 * 64];
        __shared__ float Vt[32 * 65];          // padded rows: conflict-free col reads
        int row = tid >> 3, c8 = (tid & 7) * 8;
        const float* ks = K + ((size_t)(b * S_LEN + t * 32 + row)) * 64 + c8;
        const float* vs = V + ((size_t)(b * S_LEN + t * 32 + row)) * 64 + c8;
        float4 ka = *(const float4*)ks, kb4 = *(const float4*)(ks + 4);
        float4 va = *(const float4*)vs, vb4 = *(const float4*)(vs + 4);
        *(float4*)&Kt[row * 64 + c8] = ka;
        *(float4*)&Kt[row * 64 + c8 + 4] = kb4;
        float* vr = &Vt[row * 65 + c8];
        vr[0] = va.x; vr[1] = va.y; vr[2] = va.z; vr[3] = va.w;
        vr[4] = vb4.x; vr[5] = vb4.y; vr[6] = vb4.z; vr[7] = vb4.w;
        __syncthreads();

        int j = tid >> 6, lane = tid & 63, low = lane & 15, h = lane >> 4;
        u16* tb = blob + ((size_t)(b * 256 + t)) * 4096;   // u16 elems (8 KB)
        {   // K chunk j = kt*2 + ds  (f16)
            int kt = j >> 1, ds = j & 1;
            int krow = 8 * (low >> 2) + 4 * kt + (low & 3);
            const float* src = &Kt[krow * 64 + ds * 32 + h * 8];
            u32 wds[4];
#pragma unroll
            for (int i = 0; i < 4; ++i)
                wds[i] = (u32)f2h(src[2 * i]) | ((u32)f2h(src[2 * i + 1]) << 16);
            *(int4*)(tb + j * 512 + lane * 8) = make_int4(wds[0], wds[1], wds[2], wds[3]);
        }
        {   // V chunk dt = j  (f16)
            int col = j * 16 + low;
            u32 wds[4];
#pragma unroll
            for (int i = 0; i < 4; ++i) {
                float a = Vt[(h * 8 + 2 * i) * 65 + col];
                float c = Vt[(h * 8 + 2 * i + 1) * 65 + col];
                wds[i] = (u32)f2h(a) | ((u32)f2h(c) << 16);
            }
            *(int4*)(tb + 2048 + j * 512 + lane * 8) = make_int4(wds[0], wds[1], wds[2], wds[3]);
        }
    } else {
#pragma clang fp contract(off)
        int i = (bid - 1024) * 256 + tid;
        double cr = (double)crp[0], ci = (double)cip[0], sc = (double)scp[0];
        double step = 4.0 / (double)(S_LEN - 1);
        double x = (i == S_LEN - 1) ? 2.0 : (-2.0 + step * (double)i);
        double zr = x, zi = 0.0, et = 1.0;
        bool esc = false;
        for (int it = 0; it < 64; ++it) {
            double nzr = zr * zr - zi * zi + cr;
            double nzi = 2.0 * zr * zi + ci;
            if (!esc) { zr = nzr; zi = nzi; }
            double m2 = zr * zr + zi * zi;
            if (!esc && m2 > 4.0) { et = (double)it / 64.0; esc = true; }
        }
        double bias = log(exp(et * sc) + 1e-8);
        bias2[i] = (float)(bias * 1.4426950408889634 - 20.0);
    }
}

// ---------------------------------------------------------------------------
// Flash: packed-fragment streaming, no LDS / no barriers in the main loop.
//   grid 512, block 384 = 6 waves; bid = qtile*4 + batch.  Each block =
//   one (qtile,batch): 64 q-rows x all 8192 keys, 6-way in-block split-K
//   with unequal tile counts {43,43,43,43,42,42} (BK=32; 1.2% imbalance).
//
//   OCCUPANCY PLAN (R4/R5 lessons): waves/SIMD = 512 / (arch + acc VGPRs).
//   The 64q/wave shape (o[4][4] = 64 acc, 32 MFMA per 8 KB tile load) is
//   the right arithmetic intensity (R5's 32q shape halved it and LOST 20%
//   despite 2x occupancy).  Single-buffering K/V/bias trims arch to ~105
//   -> total ~170 -> 3 waves/SIMD, enforced by amdgpu_waves_per_eu(3).
//   grid 512 x 2 blocks/CU = 12 waves/CU = EXACTLY one dispatch round (a
//   1024-block grid at 3 resident blocks/CU would quantize to 2 rounds,
//   the 2nd 1/3-full).  Monolithic output (no khalf split / merge kernel).
//
//   Single-buffer slack: K+bias(ki+1) issued right after QK(ki) consumes
//   them, consumed at QK(ki+1) -> SM+PV+Vload (~500 cyc) of cover.
//   V(ki+1) issued after PV(ki), consumed after QK+SM (~500 cyc).  3-wave
//   TLP covers the residue.  MFMA-pipe floor: 4.19M MFMA / 1024 SIMD x
//   19.4 cyc = 33 us; VALU floor ~28 us on the separate pipe.
//
//   All operands f16; fixed-max softmax (M=20 folded into bias); 6 split-K
//   partials add linearly, merged by a 2-round LDS tree (3 slots, 53 KB).
// ---------------------------------------------------------------------------
__global__ __launch_bounds__(384)
__attribute__((amdgpu_waves_per_eu(3)))
void flash_kernel(const float* __restrict__ Q, const u16* __restrict__ blob,
                  const float* __restrict__ bias2, float* __restrict__ Out) {
    __shared__ __align__(16) char smem[52992];   // 3 merge slots x 17664 B

    const int tid = threadIdx.x;
    const int l = tid & 63, low = l & 15, h = l >> 4;
    const int ks = __builtin_amdgcn_readfirstlane(tid >> 6);   // 0..5

    const int bid = blockIdx.x;
    const int batch = bid & 3;          // XCD-affinity: batch b on XCDs {b, b+4}
    const int qtile = bid >> 2;         // 0..127 (BQ = 64)
    const int q0 = qtile * 64;

    // ---- Q fragments (4 x 16 q-rows, f16), scale log2(e)/8 folded ----
    const float qscale = 0.18033688011112042f;
    half8 qfrag[4][2];
#pragma unroll
    for (int qf = 0; qf < 4; ++qf) {
        const float* qrow = Q + ((size_t)(batch * S_LEN + q0 + qf * 16 + low)) * DHEAD + h * 8;
#pragma unroll
        for (int ds = 0; ds < 2; ++ds) {
            f32x4 a = *(const f32x4*)(qrow + ds * 32);
            f32x4 b = *(const f32x4*)(qrow + ds * 32 + 4);
            HU8 u;
            u.w[0] = packh2(a[0] * qscale, a[1] * qscale);
            u.w[1] = packh2(a[2] * qscale, a[3] * qscale);
            u.w[2] = packh2(b[0] * qscale, b[1] * qscale);
            u.w[3] = packh2(b[2] * qscale, b[3] * qscale);
            qfrag[qf][ds] = u.h8;
        }
    }

    // unequal 6-way split of the 256 key-tiles: {43,43,43,43,42,42}
    const int t0  = (ks < 4) ? ks * 43 : 172 + (ks - 4) * 42;
    const int kit = (ks < 4) ? 43 : 42;

    // wave-uniform stream base (SGPR) + single lane offset (VGPR)
    const u16* kvb = blob + ((size_t)(batch * 256 + t0)) * 4096;
    const int loff = l * 8;                         // u16 elems (16 B/lane)
    const float* bbase = bias2 + t0 * 32;

    f32x4 o[4][4];
#pragma unroll
    for (int qf = 0; qf < 4; ++qf)
#pragma unroll
        for (int dt = 0; dt < 4; ++dt) o[qf][dt] = (f32x4){0, 0, 0, 0};
    float lsum[4] = {0.f, 0.f, 0.f, 0.f};

    HU8 kf[4];           // K single buffer (tile ki)
    f32x4 bvv[2];        // bias single buffer (tile ki; [kt])
    HU8 vf[4];           // V single buffer (tile ki)

    // ---- prologue: load tile 0 operands ----
#pragma unroll
    for (int j = 0; j < 4; ++j) kf[j].i4 = *(const int4*)(kvb + j * 512 + loff);
    bvv[0] = *(const f32x4*)(bbase + h * 8);
    bvv[1] = *(const f32x4*)(bbase + h * 8 + 4);
#pragma unroll
    for (int j = 0; j < 4; ++j) vf[j].i4 = *(const int4*)(kvb + 2048 + j * 512 + loff);

    // ---- main loop: QK(i) -> [issue K/bias(i+1)] -> SM(i) -> PV(i) ->
    //      [issue V(i+1)].  Last iteration prefetches one tile past the
    //      wave's range: in-blob for ks<5, blob/bias tail pad for ks=5. ----
#pragma unroll 1
    for (int ki = 0; ki < kit; ++ki) {
        // QK(ki): 16 MFMA, bias as C-init
        f32x4 st[2][4];
#pragma unroll
        for (int kt = 0; kt < 2; ++kt) {
            const f32x4 binit = kt ? bvv[1] : bvv[0];
#pragma unroll
            for (int qf = 0; qf < 4; ++qf) {
                f32x4 a = __builtin_amdgcn_mfma_f32_16x16x32_f16(kf[kt * 2].h8, qfrag[qf][0], binit, 0, 0, 0);
                a = __builtin_amdgcn_mfma_f32_16x16x32_f16(kf[kt * 2 + 1].h8, qfrag[qf][1], a, 0, 0, 0);
                st[kt][qf] = a;
            }
        }

        // issue K + bias of tile ki+1 (kf/bvv consumed by QK above; WAR is
        // safe: in-order issue means the loads write back long after the
        // MFMAs latched their operands)
        const u16* tn = kvb + ((size_t)ki + 1) * 4096;
#pragma unroll
        for (int j = 0; j < 4; ++j) kf[j].i4 = *(const int4*)(tn + j * 512 + loff);
        const float* bpn = bbase + (ki + 1) * 32 + h * 8;
        bvv[0] = *(const f32x4*)bpn;
        bvv[1] = *(const f32x4*)(bpn + 4);

        // SM(ki): exp2 + pack to f16 P-frags
        HU8 pf[4];
#pragma unroll
        for (int kt = 0; kt < 2; ++kt)
#pragma unroll
            for (int qf = 0; qf < 4; ++qf) {
                float p0 = EXP2(st[kt][qf][0]), p1 = EXP2(st[kt][qf][1]);
                float p2 = EXP2(st[kt][qf][2]), p3 = EXP2(st[kt][qf][3]);
                lsum[qf] += (p0 + p1) + (p2 + p3);
                pf[qf].w[kt * 2]     = packh2(p0, p1);
                pf[qf].w[kt * 2 + 1] = packh2(p2, p3);
            }

        // PV(ki): 16 MFMA
#pragma unroll
        for (int dt = 0; dt < 4; ++dt)
#pragma unroll
            for (int qf = 0; qf < 4; ++qf)
                o[qf][dt] = __builtin_amdgcn_mfma_f32_16x16x32_f16(vf[dt].h8, pf[qf].h8, o[qf][dt], 0, 0, 0);

        // issue V of tile ki+1 (vf consumed by PV above)
#pragma unroll
        for (int j = 0; j < 4; ++j) vf[j].i4 = *(const int4*)(tn + 2048 + j * 512 + loff);
    }

    // ---- finalize lsum across the 4 key-row groups ----
#pragma unroll
    for (int qf = 0; qf < 4; ++qf) {
        lsum[qf] += __shfl_xor(lsum[qf], 16, 64);
        lsum[qf] += __shfl_xor(lsum[qf], 32, 64);
    }

    // ---- split-K merge: partials add linearly (fixed max).
    //      6 waves -> 2-round LDS tree over 3 slots of [64][68]+[64]. ----
    auto wpart = [&](int slot) {
        float* MO = (float*)(smem + slot * 17664);
        float* ML = (float*)(smem + slot * 17664 + 17408);
#pragma unroll
        for (int qf = 0; qf < 4; ++qf) {
            const int row = qf * 16 + low;
#pragma unroll
            for (int dt = 0; dt < 4; ++dt)
                *(f32x4*)&MO[row * 68 + dt * 16 + h * 4] = o[qf][dt];
            if (h == 0) ML[row] = lsum[qf];
        }
    };
    auto apart = [&](int slot) {
        float* MO = (float*)(smem + slot * 17664);
        float* ML = (float*)(smem + slot * 17664 + 17408);
#pragma unroll
        for (int qf = 0; qf < 4; ++qf) {
            const int row = qf * 16 + low;
#pragma unroll
            for (int dt = 0; dt < 4; ++dt) {
                f32x4 a = *(const f32x4*)&MO[row * 68 + dt * 16 + h * 4];
#pragma unroll
                for (int jj = 0; jj < 4; ++jj) o[qf][dt][jj] += a[jj];
            }
            lsum[qf] += ML[row];
        }
    };

    // round 1: waves 1,3,5 write slots 0,1,2; waves 0,2,4 add them
    __syncthreads();
    if (ks & 1) wpart(ks >> 1);
    __syncthreads();
    if (!(ks & 1)) apart(ks >> 1);
    // round 2: waves 2,4 write slots 0,1; wave 0 adds both
    __syncthreads();
    if (ks == 2) wpart(0);
    if (ks == 4) wpart(1);
    __syncthreads();
    if (ks == 0) { apart(0); apart(1); }

    // ---- normalized write ----
    if (ks == 0) {
#pragma unroll
        for (int qf = 0; qf < 4; ++qf) {
            const float inv = 1.f / lsum[qf];
            float* orow = Out + ((size_t)(batch * S_LEN + q0 + qf * 16 + low)) * DHEAD;
#pragma unroll
            for (int dt = 0; dt < 4; ++dt) {
                f32x4 r;
#pragma unroll
                for (int jj = 0; jj < 4; ++jj) r[jj] = o[qf][dt][jj] * inv;
                *(f32x4*)(orow + dt * 16 + h * 4) = r;
            }
        }
    }
}

// ---------------------------------------------------------------------------
extern "C" void kernel_launch(void* const* d_in, const int* in_sizes, int n_in,
                              void* d_out, int out_size, void* d_ws, size_t ws_size,
                              hipStream_t stream) {
    const float* Q  = (const float*)d_in[0];
    const float* K  = (const float*)d_in[1];
    const float* V  = (const float*)d_in[2];
    const float* cr = (const float*)d_in[3];
    const float* ci = (const float*)d_in[4];
    const float* sc = (const float*)d_in[5];
    float* out = (float*)d_out;

    char* ws = (char*)d_ws;
    float* bias2 = (float*)ws;                   // 32 KB + 256 B tail pad  [0, 33024)
    u16*   blob  = (u16*)(ws + 33024);           // 8 MB + 8 KB tail pad

    prep_kernel<<<dim3(1056), dim3(256), 0, stream>>>(K, V, cr, ci, sc, blob, bias2);
    flash_kernel<<<dim3(512), dim3(384), 0, stream>>>(Q, blob, bias2, out);
}

// Round 7
// 147.075 us; speedup vs baseline: 1.6798x; 1.6798x over previous
//
#include <hip/hip_runtime.h>
#include <math.h>

#define S_LEN 8192
#define DHEAD 64
#define NBATCH 4
#define BK 32
#define KIT 64            // 2048 keys per kq-quarter / BK

typedef unsigned short u16;
typedef unsigned int u32;
typedef __attribute__((ext_vector_type(8))) _Float16 half8;
typedef __attribute__((ext_vector_type(2))) __fp16 fp16x2;
typedef __attribute__((ext_vector_type(4))) float f32x4;

union HU8 { int4 i4; half8 h8; u32 w[4]; };
union H2U { fp16x2 h2; u32 w; };
union HU  { _Float16 h; u16 u; };

#if __has_builtin(__builtin_amdgcn_exp2f)
#define EXP2(x) __builtin_amdgcn_exp2f(x)
#else
#define EXP2(x) exp2f(x)
#endif

// float -> f16 RNE
__device__ __forceinline__ u16 f2h(float f) {
    HU x; x.h = (_Float16)f; return x.u;
}
// two floats -> packed f16x2, single v_cvt_pkrtz_f16_f32
__device__ __forceinline__ u32 packh2(float a, float b) {
    H2U x; x.h2 = __builtin_amdgcn_cvt_pkrtz(a, b); return x.w;
}

// ---------------------------------------------------------------------------
// Prep: blocks [0,1024) pack K and V (both f16) of one 32-key tile
// (b = bid>>8, t = bid&255) into MFMA-fragment order:
//   blob[b][t] (8 KB) = K chunks j=0..3 (j=kt*2+ds) then V chunks dt=0..3,
//   chunk = 64 lanes x 16 B, exact flash lane order:
//     K: lane(low,h) -> K[b][t*32 + 8*(low>>2)+4*kt+(low&3)][ds*32+h*8+0..7]
//     V: lane(low,h) -> V[b][t*32 + h*8 + 0..7][dt*16+low]
// Blocks [1024,1056): Julia bias in f64 (matches numpy), fixed max M=20
// folded: bias2[k] = log(exp(et*scale)+1e-8)*log2e - 20.
// ---------------------------------------------------------------------------
__global__ void prep_kernel(const float* __restrict__ K, const float* __restrict__ V,
                            const float* crp, const float* cip, const float* scp,
                            u16* __restrict__ blob, float* __restrict__ bias2) {
    int bid = blockIdx.x, tid = threadIdx.x;
    if (bid < 1024) {
        int b = bid >> 8, t = bid & 255;
        __shared__ float Kt[32 * 64];
        __shared__ float Vt[32 * 65];          // padded rows: conflict-free col reads
        int row = tid >> 3, c8 = (tid & 7) * 8;
        const float* ks = K + ((size_t)(b * S_LEN + t * 32 + row)) * 64 + c8;
        const float* vs = V + ((size_t)(b * S_LEN + t * 32 + row)) * 64 + c8;
        float4 ka = *(const float4*)ks, kb4 = *(const float4*)(ks + 4);
        float4 va = *(const float4*)vs, vb4 = *(const float4*)(vs + 4);
        *(float4*)&Kt[row * 64 + c8] = ka;
        *(float4*)&Kt[row * 64 + c8 + 4] = kb4;
        float* vr = &Vt[row * 65 + c8];
        vr[0] = va.x; vr[1] = va.y; vr[2] = va.z; vr[3] = va.w;
        vr[4] = vb4.x; vr[5] = vb4.y; vr[6] = vb4.z; vr[7] = vb4.w;
        __syncthreads();

        int j = tid >> 6, lane = tid & 63, low = lane & 15, h = lane >> 4;
        u16* tb = blob + ((size_t)(b * 256 + t)) * 4096;   // u16 elems (8 KB)
        {   // K chunk j = kt*2 + ds  (f16)
            int kt = j >> 1, ds = j & 1;
            int krow = 8 * (low >> 2) + 4 * kt + (low & 3);
            const float* src = &Kt[krow * 64 + ds * 32 + h * 8];
            u32 wds[4];
#pragma unroll
            for (int i = 0; i < 4; ++i)
                wds[i] = (u32)f2h(src[2 * i]) | ((u32)f2h(src[2 * i + 1]) << 16);
            *(int4*)(tb + j * 512 + lane * 8) = make_int4(wds[0], wds[1], wds[2], wds[3]);
        }
        {   // V chunk dt = j  (f16)
            int col = j * 16 + low;
            u32 wds[4];
#pragma unroll
            for (int i = 0; i < 4; ++i) {
                float a = Vt[(h * 8 + 2 * i) * 65 + col];
                float c = Vt[(h * 8 + 2 * i + 1) * 65 + col];
                wds[i] = (u32)f2h(a) | ((u32)f2h(c) << 16);
            }
            *(int4*)(tb + 2048 + j * 512 + lane * 8) = make_int4(wds[0], wds[1], wds[2], wds[3]);
        }
    } else {
#pragma clang fp contract(off)
        int i = (bid - 1024) * 256 + tid;
        double cr = (double)crp[0], ci = (double)cip[0], sc = (double)scp[0];
        double step = 4.0 / (double)(S_LEN - 1);
        double x = (i == S_LEN - 1) ? 2.0 : (-2.0 + step * (double)i);
        double zr = x, zi = 0.0, et = 1.0;
        bool esc = false;
        for (int it = 0; it < 64; ++it) {
            double nzr = zr * zr - zi * zi + cr;
            double nzi = 2.0 * zr * zi + ci;
            if (!esc) { zr = nzr; zi = nzi; }
            double m2 = zr * zr + zi * zi;
            if (!esc && m2 > 4.0) { et = (double)it / 64.0; esc = true; }
        }
        double bias = log(exp(et * sc) + 1e-8);
        bias2[i] = (float)(bias * 1.4426950408889634 - 20.0);
    }
}

// ---------------------------------------------------------------------------
// Flash: packed-fragment streaming, no LDS / no barriers in the main loop.
//   grid 512 (2 blocks/CU), block 256 = 4 waves = 4 kq; each wave covers the
//   block's 64 q-rows (4 q-frags) x its 2048-key quarter, BK=32, 64 iters.
//
//   PHASE-ROTATED PIPELINE (this revision).  Per-SIMD busy-time invariants
//   (R0-R6): matrix pipe ~620 cyc/wave-iter, VALU+trans ~600 (32 v_exp_f32
//   at transcendental rate dominate).  R1's order QK(i)->PV(i-1)->SM(i)
//   serialized the pipes: SM(i) stalls on QK(i) results (~300 cyc) and the
//   matrix pipe idles through SM's 600 cycles.  New order per iteration:
//       QK(i) -> SM(i-1) -> PV(i-1)
//   SM(i-1) reads scores computed a FULL iteration ago (zero stall) and its
//   VALU/trans cycles issue while QK(i) executes on the matrix pipe; PV(i-1)
//   (operands: pf just computed, V(i-1) loaded last iter) refills the matrix
//   pipe.  st must live across the loop boundary -> two named buffers
//   stA/stB, explicit odd/even bodies (compile-time indices only).
//   K/V/bias are single-declared; at ~216/256 total regs (2 waves/SIMD,
//   launch_bounds(256,2) -- the only known-good setting, R2/R3/R6 all
//   spilled under tighter caps) the compiler renames across the WAR, which
//   is free double-buffering.  Occupancy stays 2 waves/SIMD BY DESIGN:
//   overlap now happens WITHIN each wave (R5/R6 proved buying occupancy
//   with shape/caps loses).
//
//   All operands f16; fixed-max softmax (M=20 folded into bias);
//   4-way split-K merged by plain adds through LDS at the end.
// ---------------------------------------------------------------------------
__global__ __launch_bounds__(256, 2)
void flash_kernel(const float* __restrict__ Q, const u16* __restrict__ blob,
                  const float* __restrict__ bias2, float* __restrict__ Out) {
    __shared__ __align__(16) char smem[17664];   // merge scratch only

    const int tid = threadIdx.x;
    const int l = tid & 63, low = l & 15, h = l >> 4;
    const int kq = __builtin_amdgcn_readfirstlane(tid >> 6);

    const int bid = blockIdx.x;
    const int batch = bid & 3;          // XCD-affinity: batch b on XCDs {b, b+4}
    const int qtile = bid >> 2;         // 0..127 (BQ = 64)
    const int q0 = qtile * 64;

    // ---- Q fragments (4 x 16 q-rows, f16), scale log2(e)/8 folded ----
    const float qscale = 0.18033688011112042f;
    half8 qfrag[4][2];
#pragma unroll
    for (int qf = 0; qf < 4; ++qf) {
        const float* qrow = Q + ((size_t)(batch * S_LEN + q0 + qf * 16 + low)) * DHEAD + h * 8;
#pragma unroll
        for (int ds = 0; ds < 2; ++ds) {
            f32x4 a = *(const f32x4*)(qrow + ds * 32);
            f32x4 b = *(const f32x4*)(qrow + ds * 32 + 4);
            HU8 u;
            u.w[0] = packh2(a[0] * qscale, a[1] * qscale);
            u.w[1] = packh2(a[2] * qscale, a[3] * qscale);
            u.w[2] = packh2(b[0] * qscale, b[1] * qscale);
            u.w[3] = packh2(b[2] * qscale, b[3] * qscale);
            qfrag[qf][ds] = u.h8;
        }
    }

    // wave-uniform stream base (SGPR) + single lane offset (VGPR)
    const u16* kvb = blob + ((size_t)(batch * 256 + kq * 64)) * 4096;
    const int loff = l * 8;                         // u16 elems (16 B/lane)
    const float* bbase = bias2 + kq * 2048;

    f32x4 o[4][4];
#pragma unroll
    for (int qf = 0; qf < 4; ++qf)
#pragma unroll
        for (int dt = 0; dt < 4; ++dt) o[qf][dt] = (f32x4){0, 0, 0, 0};
    float lsum[4] = {0.f, 0.f, 0.f, 0.f};

    HU8 kf[4];           // K buffer (compiler renames across WAR)
    f32x4 bvv[2];        // bias buffer
    HU8 vf[4];           // V buffer
    HU8 pf[4];           // P frags (SM output, PV input)
    f32x4 stA[2][4];     // score buffers: st(i) lives until SM in iter i+1
    f32x4 stB[2][4];

    // ---- prologue: QK(0) -> stA; issue K/bias(1), V(0) ----
#pragma unroll
    for (int j = 0; j < 4; ++j) kf[j].i4 = *(const int4*)(kvb + j * 512 + loff);
    bvv[0] = *(const f32x4*)(bbase + h * 8);
    bvv[1] = *(const f32x4*)(bbase + h * 8 + 4);
#pragma unroll
    for (int kt = 0; kt < 2; ++kt) {
        const f32x4 binit = kt ? bvv[1] : bvv[0];
#pragma unroll
        for (int qf = 0; qf < 4; ++qf) {
            f32x4 a = __builtin_amdgcn_mfma_f32_16x16x32_f16(kf[kt * 2].h8, qfrag[qf][0], binit, 0, 0, 0);
            a = __builtin_amdgcn_mfma_f32_16x16x32_f16(kf[kt * 2 + 1].h8, qfrag[qf][1], a, 0, 0, 0);
            stA[kt][qf] = a;
        }
    }
#pragma unroll
    for (int j = 0; j < 4; ++j) kf[j].i4 = *(const int4*)(kvb + 4096 + j * 512 + loff);
    bvv[0] = *(const f32x4*)(bbase + 32 + h * 8);
    bvv[1] = *(const f32x4*)(bbase + 32 + h * 8 + 4);
#pragma unroll
    for (int j = 0; j < 4; ++j) vf[j].i4 = *(const int4*)(kvb + 2048 + j * 512 + loff);

    // BODY(KI, STC, STP):
    //   QK(KI) -> STC            (kf=K(KI), bvv=bias(KI))
    //   issue K/bias(KI+1)       (kf/bvv WAR -> compiler renames)
    //   SM(KI-1) from STP -> pf  (scores one full iter old: no stall)
    //   PV(KI-1)                 (vf=V(KI-1))
    //   issue V(KI) -> vf
#define BODY(KI, STC, STP)                                                       \
    {                                                                            \
        const u16* tb_ = kvb + (size_t)(KI) * 4096;                              \
        const u16* tn_ = tb_ + 4096;                                             \
        _Pragma("unroll")                                                        \
        for (int kt = 0; kt < 2; ++kt) {                                         \
            const f32x4 binit = kt ? bvv[1] : bvv[0];                            \
            _Pragma("unroll")                                                    \
            for (int qf = 0; qf < 4; ++qf) {                                     \
                f32x4 a = __builtin_amdgcn_mfma_f32_16x16x32_f16(                \
                    kf[kt * 2].h8, qfrag[qf][0], binit, 0, 0, 0);                \
                a = __builtin_amdgcn_mfma_f32_16x16x32_f16(                      \
                    kf[kt * 2 + 1].h8, qfrag[qf][1], a, 0, 0, 0);                \
                STC[kt][qf] = a;                                                 \
            }                                                                    \
        }                                                                        \
        _Pragma("unroll")                                                        \
        for (int j = 0; j < 4; ++j)                                              \
            kf[j].i4 = *(const int4*)(tn_ + j * 512 + loff);                     \
        const float* bpn_ = bbase + ((KI) + 1) * 32 + h * 8;                     \
        bvv[0] = *(const f32x4*)bpn_;                                            \
        bvv[1] = *(const f32x4*)(bpn_ + 4);                                      \
        _Pragma("unroll")                                                        \
        for (int kt = 0; kt < 2; ++kt)                                           \
            _Pragma("unroll")                                                    \
            for (int qf = 0; qf < 4; ++qf) {                                     \
                float p0 = EXP2(STP[kt][qf][0]), p1 = EXP2(STP[kt][qf][1]);      \
                float p2 = EXP2(STP[kt][qf][2]), p3 = EXP2(STP[kt][qf][3]);      \
                lsum[qf] += (p0 + p1) + (p2 + p3);                               \
                pf[qf].w[kt * 2]     = packh2(p0, p1);                           \
                pf[qf].w[kt * 2 + 1] = packh2(p2, p3);                           \
            }                                                                    \
        _Pragma("unroll")                                                        \
        for (int dt = 0; dt < 4; ++dt)                                           \
            _Pragma("unroll")                                                    \
            for (int qf = 0; qf < 4; ++qf)                                       \
                o[qf][dt] = __builtin_amdgcn_mfma_f32_16x16x32_f16(              \
                    vf[dt].h8, pf[qf].h8, o[qf][dt], 0, 0, 0);                   \
        _Pragma("unroll")                                                        \
        for (int j = 0; j < 4; ++j)                                              \
            vf[j].i4 = *(const int4*)(tb_ + 2048 + j * 512 + loff);              \
    }

    // bodies 1..62 in odd/even pairs, then body 63 (its K/bias(64) prefetch
    // reads blob/bias tail pad -- dead values)
#pragma unroll 1
    for (int kp = 1; kp < KIT - 1; kp += 2) {
        BODY(kp, stB, stA)
        BODY(kp + 1, stA, stB)
    }
    BODY(KIT - 1, stB, stA)
#undef BODY

    // ---- epilogue: SM(63) from stB, PV(63) ----
#pragma unroll
    for (int kt = 0; kt < 2; ++kt)
#pragma unroll
        for (int qf = 0; qf < 4; ++qf) {
            float p0 = EXP2(stB[kt][qf][0]), p1 = EXP2(stB[kt][qf][1]);
            float p2 = EXP2(stB[kt][qf][2]), p3 = EXP2(stB[kt][qf][3]);
            lsum[qf] += (p0 + p1) + (p2 + p3);
            pf[qf].w[kt * 2]     = packh2(p0, p1);
            pf[qf].w[kt * 2 + 1] = packh2(p2, p3);
        }
#pragma unroll
    for (int dt = 0; dt < 4; ++dt)
#pragma unroll
        for (int qf = 0; qf < 4; ++qf)
            o[qf][dt] = __builtin_amdgcn_mfma_f32_16x16x32_f16(vf[dt].h8, pf[qf].h8, o[qf][dt], 0, 0, 0);

    // ---- finalize l ----
#pragma unroll
    for (int qf = 0; qf < 4; ++qf) {
        lsum[qf] += __shfl_xor(lsum[qf], 16, 64);
        lsum[qf] += __shfl_xor(lsum[qf], 32, 64);
    }

    // ---- split-K merge: partials add linearly (fixed max). 3 stages. ----
    float* MO = (float*)smem;              // [64][68]
    float* ML = (float*)(smem + 17408);    // [64]
#pragma unroll 1
    for (int src = 1; src < 4; ++src) {
        __syncthreads();
        if (kq == src) {
#pragma unroll
            for (int qf = 0; qf < 4; ++qf) {
                const int row = qf * 16 + low;
#pragma unroll
                for (int dt = 0; dt < 4; ++dt)
                    *(f32x4*)&MO[row * 68 + dt * 16 + h * 4] = o[qf][dt];
                if (h == 0) ML[row] = lsum[qf];
            }
        }
        __syncthreads();
        if (kq == 0) {
#pragma unroll
            for (int qf = 0; qf < 4; ++qf) {
                const int row = qf * 16 + low;
#pragma unroll
                for (int dt = 0; dt < 4; ++dt) {
                    f32x4 a = *(const f32x4*)&MO[row * 68 + dt * 16 + h * 4];
#pragma unroll
                    for (int jj = 0; jj < 4; ++jj) o[qf][dt][jj] += a[jj];
                }
                lsum[qf] += ML[row];
            }
        }
    }

    if (kq == 0) {
#pragma unroll
        for (int qf = 0; qf < 4; ++qf) {
            const float inv = 1.f / lsum[qf];
            float* orow = Out + ((size_t)(batch * S_LEN + q0 + qf * 16 + low)) * DHEAD;
#pragma unroll
            for (int dt = 0; dt < 4; ++dt) {
                f32x4 r;
#pragma unroll
                for (int jj = 0; jj < 4; ++jj) r[jj] = o[qf][dt][jj] * inv;
                *(f32x4*)(orow + dt * 16 + h * 4) = r;
            }
        }
    }
}

// ---------------------------------------------------------------------------
extern "C" void kernel_launch(void* const* d_in, const int* in_sizes, int n_in,
                              void* d_out, int out_size, void* d_ws, size_t ws_size,
                              hipStream_t stream) {
    const float* Q  = (const float*)d_in[0];
    const float* K  = (const float*)d_in[1];
    const float* V  = (const float*)d_in[2];
    const float* cr = (const float*)d_in[3];
    const float* ci = (const float*)d_in[4];
    const float* sc = (const float*)d_in[5];
    float* out = (float*)d_out;

    char* ws = (char*)d_ws;
    float* bias2 = (float*)ws;                   // 32 KB + 256 B tail pad  [0, 33024)
    u16*   blob  = (u16*)(ws + 33024);           // 8 MB + 8 KB tail pad

    prep_kernel<<<dim3(1056), dim3(256), 0, stream>>>(K, V, cr, ci, sc, blob, bias2);
    flash_kernel<<<dim3(512), dim3(256), 0, stream>>>(Q, blob, bias2, out);
}